// Round 4
// baseline (473.382 us; speedup 1.0000x reference)
//
#include <hip/hip_runtime.h>

#define BATCH 8
#define CHN 128
#define HH 160
#define WW 160
#define HW (HH*WW)
#define RR 2
#define MAXOFF 5
#define NOFF 25
#define TW 32
#define TH 8
#define PW (TW + 2*RR)     /* 36 */
#define PH (TH + 2*RR)     /* 12 */
#define NG 4
#define CPG (CHN/NG)       /* 32 channels per group */
#define RC 4               /* channels per group per round */
#define SCH (NG*RC)        /* 16 staged channels per round */
#define ROUNDS (CPG/RC)    /* 8 */
#define NPT (TW/2*TH)      /* 128 pixel-threads per group */
#define NTHREADS 512
#define CHFL (PH*PW)       /* 432 floats per staged channel */
#define STFL (SCH*CHFL)    /* 6912 floats per LDS buffer */
#define NSLOT ((STFL + NTHREADS - 1) / NTHREADS)  /* 14 staging slots/thread */
#define OCH 5              /* epilogue offset chunk */

__device__ __forceinline__ int reflect_idx(int i, int n) {
    if (i < 0) i = -i;
    if (i >= n) i = 2 * (n - 1) - i;
    return i;
}

__global__ __launch_bounds__(NTHREADS, 4) void costvol_kernel(
    const float* __restrict__ c1,
    const float* __restrict__ c2,
    const float* __restrict__ pw,
    float* __restrict__ out)
{
    __shared__ float buf[2][STFL];   // 2 x 27648 B = 55296 B

    const int tid = threadIdx.x;
    const int g  = tid >> 7;            // channel group 0..3
    const int pt = tid & (NPT - 1);     // pixel-thread 0..127
    const int xh = pt & (TW/2 - 1);     // float2 column 0..15
    const int y  = pt >> 4;             // row 0..7
    const int x0 = xh * 2;

    int bidx = blockIdx.x;
    const int tx0 = (bidx % (WW / TW)) * TW; bidx /= (WW / TW);
    const int ty0 = (bidx % (HH / TH)) * TH; bidx /= (HH / TH);
    const int b = bidx;

    const float* c1p = c1 + ((size_t)b * CHN + g * CPG) * HW + (ty0 + y) * WW + tx0 + x0;
    const float* c2b = c2 + (size_t)b * CHN * HW;

    // ---- precompute per-thread staging descriptors (round-invariant) ----
    // slot k stages lds element idx = tid + k*512; source plane offset for r=0.
    int soff[NSLOT];
#pragma unroll
    for (int k = 0; k < NSLOT; ++k) {
        const int idx = tid + k * NTHREADS;
        if (idx < STFL) {
            int c   = idx / CHFL;           // staged slot 0..15  (c = g2*RC + j)
            int rem = idx - c * CHFL;
            int ty  = rem / PW;
            int tx  = rem - ty * PW;
            int g2  = c >> 2, j = c & 3;
            int gr  = reflect_idx(ty0 - RR + ty, HH);
            int gc  = reflect_idx(tx0 - RR + tx, WW);
            soff[k] = (g2 * CPG + j) * HW + gr * WW + gc;
        } else {
            soff[k] = -1;
        }
    }

    // ---- async staging: global -> LDS, one dword per lane per slot ----
    auto stage = [&](float* dst, int r) {
        const float* src_base = c2b + (size_t)r * RC * HW;
#pragma unroll
        for (int k = 0; k < NSLOT; ++k) {
            if (soff[k] >= 0) {
                __builtin_amdgcn_global_load_lds(
                    (const __attribute__((address_space(1))) void*)(src_base + soff[k]),
                    (__attribute__((address_space(3))) void*)(dst + tid + k * NTHREADS),
                    4, 0, 0);
            }
        }
    };

    float2 acc2[NOFF];
#pragma unroll
    for (int i = 0; i < NOFF; ++i) acc2[i] = make_float2(0.f, 0.f);

    // prologue: buffer 0 <- round 0; then issue round 1 into buffer 1
    stage(buf[0], 0);
    __syncthreads();                 // drains vmcnt(0) + barrier
    stage(buf[1], 1);

    int cur = 0;
    for (int r = 0; r < ROUNDS; ++r) {
        const float* cbuf = buf[cur];
        const float2* lds2 = (const float2*)cbuf;
#pragma unroll
        for (int j = 0; j < RC; ++j) {
            const float2 s = *(const float2*)(c1p + (size_t)(r * RC + j) * HW);
            const float2* t2 = lds2 + (g * RC + j) * (CHFL / 2);
#pragma unroll
            for (int dy = 0; dy < MAXOFF; ++dy) {
                const int rb = (y + dy) * (PW / 2) + xh;
                const float2 w0 = t2[rb + 0];
                const float2 w1 = t2[rb + 1];
                const float2 w2 = t2[rb + 2];
                float2* A = &acc2[dy * MAXOFF];
                A[0].x = fmaf(s.x, w0.x, A[0].x);  A[0].y = fmaf(s.y, w0.y, A[0].y);
                A[1].x = fmaf(s.x, w0.y, A[1].x);  A[1].y = fmaf(s.y, w1.x, A[1].y);
                A[2].x = fmaf(s.x, w1.x, A[2].x);  A[2].y = fmaf(s.y, w1.y, A[2].y);
                A[3].x = fmaf(s.x, w1.y, A[3].x);  A[3].y = fmaf(s.y, w2.x, A[3].y);
                A[4].x = fmaf(s.x, w2.x, A[4].x);  A[4].y = fmaf(s.y, w2.y, A[4].y);
            }
        }
        __syncthreads();             // drains r+1's loads; all readers of buf[cur] done
        if (r + 2 < ROUNDS) stage(buf[cur], r + 2);   // refill the freed buffer
        cur ^= 1;
    }

    // ---- cross-group reduction through LDS, then scale + PReLU + store ----
    const float a = pw[0];
    const float inv_c = 1.0f / (float)CHN;
    float2* e2 = (float2*)&buf[0][0];   // 3*OCH*NPT float2 = 15360 B, fits in buf[0]

#pragma unroll
    for (int o0 = 0; o0 < NOFF; o0 += OCH) {
        __syncthreads();
        if (g > 0) {
#pragma unroll
            for (int k = 0; k < OCH; ++k)
                e2[((g - 1) * OCH + k) * NPT + pt] = acc2[o0 + k];
        }
        __syncthreads();
        if (g == 0) {
#pragma unroll
            for (int k = 0; k < OCH; ++k) {
                const int o = o0 + k;
                float2 v  = acc2[o];
                float2 v1 = e2[(0 * OCH + k) * NPT + pt];
                float2 v2 = e2[(1 * OCH + k) * NPT + pt];
                float2 v3 = e2[(2 * OCH + k) * NPT + pt];
                float vx = (v.x + v1.x + v2.x + v3.x) * inv_c;
                float vy = (v.y + v1.y + v2.y + v3.y) * inv_c;
                vx = (vx >= 0.f) ? vx : a * vx;
                vy = (vy >= 0.f) ? vy : a * vy;
                *(float2*)(out + (size_t)(b * NOFF + o) * HW + (ty0 + y) * WW + tx0 + x0)
                    = make_float2(vx, vy);
            }
        }
    }
}

extern "C" void kernel_launch(void* const* d_in, const int* in_sizes, int n_in,
                              void* d_out, int out_size, void* d_ws, size_t ws_size,
                              hipStream_t stream) {
    const float* c1 = (const float*)d_in[0];
    const float* c2 = (const float*)d_in[1];
    const float* pw = (const float*)d_in[2];
    float* out = (float*)d_out;

    dim3 grid((WW / TW) * (HH / TH) * BATCH);   // 5*20*8 = 800 blocks
    dim3 block(NTHREADS);
    costvol_kernel<<<grid, block, 0, stream>>>(c1, c2, pw, out);
}

// Round 5
// 83.879 us; speedup vs baseline: 5.6436x; 5.6436x over previous
//
#include <hip/hip_runtime.h>

#define BATCH 8
#define CHN 128
#define HH 160
#define WW 160
#define HW (HH*WW)
#define RR 2
#define MAXOFF 5
#define NOFF 25
#define TW 32
#define TH 8
#define PW (TW + 2*RR)     /* 36 */
#define PH (TH + 2*RR)     /* 12 */
#define NG 2
#define CPG (CHN/NG)       /* 64 channels per group */
#define RC 4               /* channels per group per round */
#define SCH (NG*RC)        /* 8 staged channels per round */
#define ROUNDS (CPG/RC)    /* 16 */
#define NPT 128            /* float2 pixel-threads per group */
#define NTHREADS 256
#define CHFL (PH*PW)       /* 432 floats per staged channel */
#define STFL (SCH*CHFL)    /* 3456 floats staged per round */
#define NSLOT 14           /* ceil(STFL/NTHREADS) */
#define EPFL (NOFF*NPT*2)  /* 6400 floats for epilogue exchange */

__device__ __forceinline__ int reflect_idx(int i, int n) {
    if (i < 0) i = -i;
    if (i >= n) i = 2 * (n - 1) - i;
    return i;
}

__global__ __launch_bounds__(NTHREADS) void costvol_kernel(
    const float* __restrict__ c1,
    const float* __restrict__ c2,
    const float* __restrict__ pw,
    float* __restrict__ out)
{
    __shared__ float lds[EPFL];        // 25600 B (staging uses first 13824 B)

    const int tid = threadIdx.x;
    const int g  = tid >> 7;           // channel group 0..1
    const int pt = tid & (NPT - 1);    // pixel-thread 0..127
    const int xh = pt & 15;            // float2 column 0..15
    const int y  = pt >> 4;            // row 0..7

    int bidx = blockIdx.x;
    const int tx0 = (bidx % (WW / TW)) * TW; bidx /= (WW / TW);
    const int ty0 = (bidx % (HH / TH)) * TH; bidx /= (HH / TH);
    const int b = bidx;

    // ---- round-invariant staging byte offsets (14 VGPRs, computed once) ----
    int boff[NSLOT];
#pragma unroll
    for (int k = 0; k < NSLOT; ++k) {
        const int idx = tid + k * NTHREADS;
        if (idx < STFL) {
            int c   = idx / CHFL;          // staged slot 0..7
            int rem = idx - c * CHFL;
            int ty  = rem / PW;
            int tx  = rem - ty * PW;
            int gh  = c >> 2, j = c & 3;   // group-half, channel-within-round
            int gr  = reflect_idx(ty0 - RR + ty, HH);
            int gc  = reflect_idx(tx0 - RR + tx, WW);
            boff[k] = ((gh * CPG + j) * HW + gr * WW + gc) * 4;
        } else {
            boff[k] = 0;                   // dead slots (tid>=128 at k=13)
        }
    }

    const char*  c2b = (const char*)(c2 + (size_t)b * CHN * HW);
    const float* c1p = c1 + ((size_t)b * CHN + g * CPG) * HW
                          + (ty0 + y) * WW + tx0 + xh * 2;

    float  sv[NSLOT];     // staged c2 values in flight
    float2 sc[RC], sn[RC];

    auto issue_c2 = [&](int r) {
        const char* base = c2b + (size_t)r * RC * HW * 4;
#pragma unroll
        for (int k = 0; k < NSLOT; ++k)
            if (tid + k * NTHREADS < STFL)
                sv[k] = *(const float*)(base + boff[k]);
    };
    auto write_lds = [&]() {
#pragma unroll
        for (int k = 0; k < NSLOT; ++k)
            if (tid + k * NTHREADS < STFL)
                lds[tid + k * NTHREADS] = sv[k];
    };
    auto issue_c1 = [&](int r, float2* dst) {
#pragma unroll
        for (int j = 0; j < RC; ++j)
            dst[j] = *(const float2*)(c1p + (size_t)(r * RC + j) * HW);
    };

    float2 acc2[NOFF];
#pragma unroll
    for (int i = 0; i < NOFF; ++i) acc2[i] = make_float2(0.f, 0.f);

    // ---- prologue: stage round 0, prefetch round 1 ----
    issue_c2(0);
    issue_c1(0, sc);
    write_lds();
    __syncthreads();                   // lds holds round 0
    issue_c2(1);
    issue_c1(1, sn);

    for (int r = 0; r < ROUNDS; ++r) {
        // compute round r from lds + sc (overlaps round r+1's global loads)
        const float2* lbase = (const float2*)lds + g * RC * (CHFL / 2)
                            + y * (PW / 2) + xh;
#pragma unroll
        for (int j = 0; j < RC; ++j) {
            const float2 s = sc[j];
            const float2* t2 = lbase + j * (CHFL / 2);
#pragma unroll
            for (int dy = 0; dy < MAXOFF; ++dy) {
                const float2 w0 = t2[dy * (PW / 2) + 0];
                const float2 w1 = t2[dy * (PW / 2) + 1];
                const float2 w2 = t2[dy * (PW / 2) + 2];
                float2* A = &acc2[dy * MAXOFF];
                A[0].x = fmaf(s.x, w0.x, A[0].x);  A[0].y = fmaf(s.y, w0.y, A[0].y);
                A[1].x = fmaf(s.x, w0.y, A[1].x);  A[1].y = fmaf(s.y, w1.x, A[1].y);
                A[2].x = fmaf(s.x, w1.x, A[2].x);  A[2].y = fmaf(s.y, w1.y, A[2].y);
                A[3].x = fmaf(s.x, w1.y, A[3].x);  A[3].y = fmaf(s.y, w2.x, A[3].y);
                A[4].x = fmaf(s.x, w2.x, A[4].x);  A[4].y = fmaf(s.y, w2.y, A[4].y);
            }
        }
        __syncthreads();               // everyone done reading lds (round r)
        if (r + 1 < ROUNDS) {
            write_lds();               // waits on round r+1's loads, writes them
#pragma unroll
            for (int j = 0; j < RC; ++j) sc[j] = sn[j];
            __syncthreads();           // lds holds round r+1
            if (r + 2 < ROUNDS) {
                issue_c2(r + 2);       // overlap with next compute
                issue_c1(r + 2, sn);
            }
        }
    }

    // ---- cross-group reduction + scale + PReLU + store ----
    const float a = pw[0];
    const float inv_c = 1.0f / (float)CHN;

    __syncthreads();
    if (g == 1) {
        float2* e2 = (float2*)lds;
#pragma unroll
        for (int o = 0; o < NOFF; ++o)
            e2[o * NPT + pt] = acc2[o];
    }
    __syncthreads();
    if (g == 0) {
        const float2* e2 = (const float2*)lds;
        float* op = out + (size_t)b * NOFF * HW + (ty0 + y) * WW + tx0 + xh * 2;
#pragma unroll
        for (int o = 0; o < NOFF; ++o) {
            float2 v1 = e2[o * NPT + pt];
            float vx = (acc2[o].x + v1.x) * inv_c;
            float vy = (acc2[o].y + v1.y) * inv_c;
            vx = (vx >= 0.f) ? vx : a * vx;
            vy = (vy >= 0.f) ? vy : a * vy;
            *(float2*)(op + (size_t)o * HW) = make_float2(vx, vy);
        }
    }
}

extern "C" void kernel_launch(void* const* d_in, const int* in_sizes, int n_in,
                              void* d_out, int out_size, void* d_ws, size_t ws_size,
                              hipStream_t stream) {
    const float* c1 = (const float*)d_in[0];
    const float* c2 = (const float*)d_in[1];
    const float* pw = (const float*)d_in[2];
    float* out = (float*)d_out;

    dim3 grid((WW / TW) * (HH / TH) * BATCH);   // 5*20*8 = 800 blocks
    dim3 block(NTHREADS);
    costvol_kernel<<<grid, block, 0, stream>>>(c1, c2, pw, out);
}